// Round 1
// baseline (227.791 us; speedup 1.0000x reference)
//
#include <hip/hip_runtime.h>
#include <hip/hip_bf16.h>
#include <math.h>

// Problem constants (match reference setup_inputs)
// B=8, N=32, S=512, H=768, K=3, C=128, L=64, W=16, Tp=496, Ts=511
#define NEG_INF (-1e30f)

// ---------------------------------------------------------------------------
// Kernel 1: build transposed weight matrix Wt[h][j], j = ws*384 + k*128 + c
//           ws: 0=prefix, 1=span, 2=suffix; source w[ws][c][h][k]
// ---------------------------------------------------------------------------
__global__ __launch_bounds__(256) void transpose_w(
    const float* __restrict__ span_w, const float* __restrict__ prefix_w,
    const float* __restrict__ suffix_w, float* __restrict__ Wt) {
  int idx = blockIdx.x * 256 + threadIdx.x;  // over 768*1152
  if (idx >= 768 * 1152) return;
  int h = idx / 1152;
  int j = idx % 1152;
  int ws = j / 384;
  int r = j % 384;
  int k = r / 128;
  int c = r % 128;
  const float* w = (ws == 0) ? prefix_w : (ws == 1) ? span_w : suffix_w;
  Wt[idx] = w[(c * 768 + h) * 3 + k];
}

// ---------------------------------------------------------------------------
// Kernel 2: GEMM  Ct[j][m] = sum_h A[m][h] * Wt[h][j]
//   A = tokens_emb [4096 x 768] row-major, Wt [768 x 1152], Ct [1152 x 4096]
//   64x64 tile, BK=16, 256 threads, 4x4 micro-tile / thread
// ---------------------------------------------------------------------------
__global__ __launch_bounds__(256) void gemm_ct(const float* __restrict__ A,
                                               const float* __restrict__ Bw,
                                               float* __restrict__ Ct) {
  const int N = 1152;
  __shared__ float As[16][64];  // [k][m]
  __shared__ float Bs[16][64];  // [k][n]
  int bx = blockIdx.x, by = blockIdx.y;
  int tid = threadIdx.x;
  int tx = tid & 15, ty = tid >> 4;
  int arow = tid >> 2, acol4 = (tid & 3) << 2;   // A tile: 64 rows x 16 k
  int brow = tid >> 4, bcol4 = (tid & 15) << 2;  // B tile: 16 k x 64 cols
  const float* Aptr = A + (size_t)(by * 64 + arow) * 768 + acol4;
  const float* Bptr = Bw + (size_t)brow * N + bx * 64 + bcol4;
  float acc[4][4] = {};
  for (int k0 = 0; k0 < 768; k0 += 16) {
    float4 av = *(const float4*)(Aptr + k0);
    float4 bv = *(const float4*)(Bptr + (size_t)k0 * N);
    __syncthreads();
    As[acol4 + 0][arow] = av.x;
    As[acol4 + 1][arow] = av.y;
    As[acol4 + 2][arow] = av.z;
    As[acol4 + 3][arow] = av.w;
    *(float4*)&Bs[brow][bcol4] = bv;
    __syncthreads();
#pragma unroll
    for (int k = 0; k < 16; ++k) {
      float4 a4 = *(const float4*)&As[k][ty << 2];
      float4 b4 = *(const float4*)&Bs[k][tx << 2];
      float a[4] = {a4.x, a4.y, a4.z, a4.w};
      float b[4] = {b4.x, b4.y, b4.z, b4.w};
#pragma unroll
      for (int i = 0; i < 4; i++)
#pragma unroll
        for (int j = 0; j < 4; j++) acc[i][j] = fmaf(a[i], b[j], acc[i][j]);
    }
  }
  int m0 = by * 64 + (ty << 2);
  int j0 = bx * 64 + (tx << 2);
#pragma unroll
  for (int j = 0; j < 4; j++) {
    float4 o = make_float4(acc[0][j], acc[1][j], acc[2][j], acc[3][j]);
    *(float4*)(Ct + (size_t)(j0 + j) * 4096 + m0) = o;
  }
}

// ---------------------------------------------------------------------------
// Kernel 3: per-(b,c) combine taps into Y and do prefix-max / suffix-max scans
//   PM2[b][c][t] = max_{q<=t} Yp[q]   (t < 494; Yp[t]=p0[t]+p1[t+1]+p2[t+2])
//   SM2[b][c][t] = max_{q>=t, q<=Lb-3} Ys[q]
//   grid = B*C = 1024 blocks of 1 wave (64 threads)
// ---------------------------------------------------------------------------
__global__ __launch_bounds__(64) void scan_kernel(const float* __restrict__ Ct,
                                                  const int* __restrict__ wsl,
                                                  float* __restrict__ PM2,
                                                  float* __restrict__ SM2) {
  int b = blockIdx.x >> 7;
  int c = blockIdx.x & 127;
  int lane = threadIdx.x;
  int mb = b * 512;
  int t0 = lane * 8;
  // ---- prefix running max ----
  const float* p0 = Ct + (size_t)(0 + c) * 4096 + mb;
  const float* p1 = Ct + (size_t)(128 + c) * 4096 + mb;
  const float* p2 = Ct + (size_t)(256 + c) * 4096 + mb;
  float v[8];
#pragma unroll
  for (int i = 0; i < 8; i++) {
    int t = t0 + i;
    v[i] = (t < 494) ? (p0[t] + p1[t + 1] + p2[t + 2]) : NEG_INF;
  }
#pragma unroll
  for (int i = 1; i < 8; i++) v[i] = fmaxf(v[i], v[i - 1]);
  float x = v[7];
#pragma unroll
  for (int d = 1; d < 64; d <<= 1) {
    float y = __shfl_up(x, d);
    if (lane >= d) x = fmaxf(x, y);
  }
  float excl = __shfl_up(x, 1);
  if (lane == 0) excl = NEG_INF;
  float* pm = PM2 + (size_t)(b * 128 + c) * 512;
#pragma unroll
  for (int i = 0; i < 8; i++) {
    int t = t0 + i;
    if (t < 494) pm[t] = fmaxf(v[i], excl);
  }
  // ---- suffix max (reverse scan) ----
  const float* s0 = Ct + (size_t)(768 + c) * 4096 + mb;
  const float* s1 = Ct + (size_t)(896 + c) * 4096 + mb;
  const float* s2 = Ct + (size_t)(1024 + c) * 4096 + mb;
  int qmax = wsl[b] - 3;
  if (qmax > 509) qmax = 509;
  float u[8];
#pragma unroll
  for (int i = 0; i < 8; i++) {
    int q = t0 + i;
    u[i] = (q <= qmax) ? (s0[q] + s1[q + 1] + s2[q + 2]) : NEG_INF;
  }
#pragma unroll
  for (int i = 6; i >= 0; i--) u[i] = fmaxf(u[i], u[i + 1]);
  float xr = u[0];
#pragma unroll
  for (int d = 1; d < 64; d <<= 1) {
    float y = __shfl_down(xr, d);
    if (lane < 64 - d) xr = fmaxf(xr, y);
  }
  float exclr = __shfl_down(xr, 1);
  if (lane == 63) exclr = NEG_INF;
  float* sm = SM2 + (size_t)(b * 128 + c) * 512;
#pragma unroll
  for (int i = 0; i < 8; i++) sm[t0 + i] = fmaxf(u[i], exclr);
}

// ---------------------------------------------------------------------------
// Kernel 4: per-span feature assembly + FC + sigmoid + threshold
//   grid = 256 spans, 128 threads (c). Boundary-window algebra:
//   prefix (T=496): full p<=s-3 -> PM2[s-3]; p=s-2 (s<=495): w0@s-2 + w1@s-1;
//     p=s-1 (s<=494): w0@s-1; all-zero windows iff s<=493 -> include 0.
//   span (T=16, w=e-s in [1,16]): full p<=w-3; p=w-2 (2<=w<=15); p=w-1 (w<=14);
//     zero iff w<=13.
//   suffix (T=511): full q in [e, Lb-3] -> SM2[e]; p=Lb-2-e in [0,508]:
//     w0@Lb-2 + w1@Lb-1; p=Lb-1-e in [0,508]: w0@Lb-1; zero iff Lb-e<=508.
// ---------------------------------------------------------------------------
__global__ __launch_bounds__(128) void span_kernel(
    const float* __restrict__ Ct, const float* __restrict__ PM2,
    const float* __restrict__ SM2, const float* __restrict__ prefix_b,
    const float* __restrict__ span_b, const float* __restrict__ suffix_b,
    const float* __restrict__ fc_w, const float* __restrict__ fc_b,
    const int* __restrict__ spans, const int* __restrict__ wsl,
    float* __restrict__ out) {
  __shared__ float sfeat[384];
  int sp = blockIdx.x;
  int b = sp >> 5;
  int c = threadIdx.x;
  int s = spans[sp * 2], e = spans[sp * 2 + 1];
  int Lb = wsl[b];
  int mb = b * 512;
  {  // prefix
    const float* t0p = Ct + (size_t)c * 4096 + mb;
    const float* t1p = Ct + (size_t)(128 + c) * 4096 + mb;
    float m = NEG_INF;
    if (s >= 3) m = fmaxf(m, PM2[(size_t)(b * 128 + c) * 512 + s - 3]);
    if (s >= 2 && s <= 495) m = fmaxf(m, t0p[s - 2] + t1p[s - 1]);
    if (s >= 1 && s <= 494) m = fmaxf(m, t0p[s - 1]);
    if (s <= 493) m = fmaxf(m, 0.0f);
    sfeat[c] = m + prefix_b[c];
  }
  {  // span
    const float* u0 = Ct + (size_t)(384 + c) * 4096 + mb;
    const float* u1 = Ct + (size_t)(512 + c) * 4096 + mb;
    const float* u2 = Ct + (size_t)(640 + c) * 4096 + mb;
    int w = e - s;
    float m = NEG_INF;
    for (int p = 0; p + 2 < w; ++p)
      m = fmaxf(m, u0[s + p] + u1[s + p + 1] + u2[s + p + 2]);
    if (w >= 2 && w <= 15) m = fmaxf(m, u0[s + w - 2] + u1[s + w - 1]);
    if (w <= 14) m = fmaxf(m, u0[s + w - 1]);
    if (w <= 13) m = fmaxf(m, 0.0f);
    sfeat[128 + c] = m + span_b[c];
  }
  {  // suffix
    const float* x0 = Ct + (size_t)(768 + c) * 4096 + mb;
    const float* x1 = Ct + (size_t)(896 + c) * 4096 + mb;
    float m = NEG_INF;
    if (e <= Lb - 3) m = fmaxf(m, SM2[(size_t)(b * 128 + c) * 512 + e]);
    int p2v = Lb - 2 - e;
    if (p2v >= 0 && p2v <= 508) m = fmaxf(m, x0[Lb - 2] + x1[Lb - 1]);
    int p1v = Lb - 1 - e;
    if (p1v >= 0 && p1v <= 508) m = fmaxf(m, x0[Lb - 1]);
    if (Lb - e <= 508) m = fmaxf(m, 0.0f);
    sfeat[256 + c] = m + suffix_b[c];
  }
  __syncthreads();
  if (c < 64) {
    float acc = fc_b[c];
    const float* wrow = fc_w + c * 384;
#pragma unroll 4
    for (int i = 0; i < 384; ++i) acc = fmaf(sfeat[i], wrow[i], acc);
    float pr = 1.0f / (1.0f + expf(-acc));
    out[sp * 64 + c] = pr;                               // probs (fp32)
    out[16384 + sp * 64 + c] = (pr > 0.5f) ? 1.0f : 0.0f;  // pred_ids
  }
}

// ---------------------------------------------------------------------------
extern "C" void kernel_launch(void* const* d_in, const int* in_sizes, int n_in,
                              void* d_out, int out_size, void* d_ws,
                              size_t ws_size, hipStream_t stream) {
  const float* tokens = (const float*)d_in[0];
  const float* span_w = (const float*)d_in[1];
  const float* span_b = (const float*)d_in[2];
  const float* prefix_w = (const float*)d_in[3];
  const float* prefix_b = (const float*)d_in[4];
  const float* suffix_w = (const float*)d_in[5];
  const float* suffix_b = (const float*)d_in[6];
  const float* fc_w = (const float*)d_in[7];
  const float* fc_b = (const float*)d_in[8];
  const int* spans = (const int*)d_in[9];
  const int* wsl = (const int*)d_in[10];
  float* out = (float*)d_out;

  char* ws = (char*)d_ws;
  float* Ct = (float*)ws;                          // 1152*4096*4 = 18874368 B
  float* Wt = (float*)(ws + 18874368);             // 768*1152*4  =  3538944 B
  float* PM2 = (float*)(ws + 18874368 + 3538944);  // 8*128*512*4 =  2097152 B
  float* SM2 = (float*)(ws + 18874368 + 3538944 + 2097152);  // 2097152 B

  hipLaunchKernelGGL(transpose_w, dim3(3456), dim3(256), 0, stream, span_w,
                     prefix_w, suffix_w, Wt);
  hipLaunchKernelGGL(gemm_ct, dim3(18, 64), dim3(256), 0, stream, tokens, Wt,
                     Ct);
  hipLaunchKernelGGL(scan_kernel, dim3(1024), dim3(64), 0, stream, Ct, wsl,
                     PM2, SM2);
  hipLaunchKernelGGL(span_kernel, dim3(256), dim3(128), 0, stream, Ct, PM2,
                     SM2, prefix_b, span_b, suffix_b, fc_w, fc_b, spans, wsl,
                     out);
}

// Round 2
// 226.197 us; speedup vs baseline: 1.0070x; 1.0070x over previous
//
#include <hip/hip_runtime.h>
#include <hip/hip_bf16.h>
#include <math.h>

// B=8, N=32, S=512, H=768, K=3, C=128, L=64, W=16
#define NEG_INF (-1e30f)

// ---------------------------------------------------------------------------
// Kernel 1: build Wt[h][j] (j = ws*384 + k*128 + c) and fcT[i][c] (i<384,c<64)
// ---------------------------------------------------------------------------
__global__ __launch_bounds__(256) void transpose_w(
    const float* __restrict__ span_w, const float* __restrict__ prefix_w,
    const float* __restrict__ suffix_w, const float* __restrict__ fc_w,
    float* __restrict__ Wt, float* __restrict__ fcT) {
  int idx = blockIdx.x * 256 + threadIdx.x;
  if (idx < 768 * 1152) {
    int h = idx / 1152;
    int j = idx % 1152;
    int ws = j / 384;
    int r = j % 384;
    int k = r / 128;
    int c = r % 128;
    const float* w = (ws == 0) ? prefix_w : (ws == 1) ? span_w : suffix_w;
    Wt[idx] = w[(c * 768 + h) * 3 + k];
  } else if (idx < 768 * 1152 + 384 * 64) {
    int r = idx - 768 * 1152;  // r = i*64 + c
    int i = r >> 6;
    int c = r & 63;
    fcT[r] = fc_w[c * 384 + i];
  }
}

// ---------------------------------------------------------------------------
// Kernel 2: GEMM  Ct[j][m] = sum_h A[m][h] * Wt[h][j]
//   A [4096 x 768], Wt [768 x 1152], Ct [1152 x 4096]
//   Tile: 128(m) x 64(j), BK=16, 256 threads, 8x4 micro-tile.
//   Thread map: m-frag on tid>>4 (4 distinct LDS addrs/wave, broadcast x16),
//   j-frag on tid&15. ~70 VGPR -> ~4 blocks/CU resident. Grid 18x32 = 576.
// ---------------------------------------------------------------------------
__global__ __launch_bounds__(256) void gemm_ct(const float* __restrict__ A,
                                               const float* __restrict__ Bw,
                                               float* __restrict__ Ct) {
  __shared__ float As[16][128];
  __shared__ float Bs[16][64];
  const int bj = blockIdx.x * 64;
  const int bm = blockIdx.y * 128;
  const int tid = threadIdx.x;
  // staging indices
  const int am = tid >> 1;            // 0..127
  const int ak = (tid & 1) * 8;       // 0 or 8
  const int bk = tid >> 4;            // 0..15
  const int bj4 = (tid & 15) * 4;     // 0..60
  const float* Ap = A + (size_t)(bm + am) * 768 + ak;
  const float* Bp = Bw + (size_t)bk * 1152 + bj + bj4;
  // compute indices
  const int m0l = (tid >> 4) * 8;
  const int j0l = (tid & 15) * 4;
  float acc[8][4] = {};
  for (int k0 = 0; k0 < 768; k0 += 16) {
    float4 a0 = *(const float4*)(Ap + k0);
    float4 a1 = *(const float4*)(Ap + k0 + 4);
    float4 b0 = *(const float4*)(Bp + (size_t)k0 * 1152);
    __syncthreads();
    As[ak + 0][am] = a0.x;
    As[ak + 1][am] = a0.y;
    As[ak + 2][am] = a0.z;
    As[ak + 3][am] = a0.w;
    As[ak + 4][am] = a1.x;
    As[ak + 5][am] = a1.y;
    As[ak + 6][am] = a1.z;
    As[ak + 7][am] = a1.w;
    *(float4*)&Bs[bk][bj4] = b0;
    __syncthreads();
#pragma unroll
    for (int k = 0; k < 16; ++k) {
      float a[8], b[4];
      *(float4*)&a[0] = *(const float4*)&As[k][m0l];
      *(float4*)&a[4] = *(const float4*)&As[k][m0l + 4];
      *(float4*)&b[0] = *(const float4*)&Bs[k][j0l];
#pragma unroll
      for (int i = 0; i < 8; ++i)
#pragma unroll
        for (int j = 0; j < 4; ++j) acc[i][j] = fmaf(a[i], b[j], acc[i][j]);
    }
  }
  const int j0 = bj + j0l;
  const int m0 = bm + m0l;
#pragma unroll
  for (int j = 0; j < 4; ++j) {
    float4 o0 = make_float4(acc[0][j], acc[1][j], acc[2][j], acc[3][j]);
    float4 o1 = make_float4(acc[4][j], acc[5][j], acc[6][j], acc[7][j]);
    *(float4*)(Ct + (size_t)(j0 + j) * 4096 + m0) = o0;
    *(float4*)(Ct + (size_t)(j0 + j) * 4096 + m0 + 4) = o1;
  }
}

// ---------------------------------------------------------------------------
// Kernel 3: per-(b,c) tap-combine + prefix-max / suffix-max scans
// ---------------------------------------------------------------------------
__global__ __launch_bounds__(64) void scan_kernel(const float* __restrict__ Ct,
                                                  const int* __restrict__ wsl,
                                                  float* __restrict__ PM2,
                                                  float* __restrict__ SM2) {
  int b = blockIdx.x >> 7;
  int c = blockIdx.x & 127;
  int lane = threadIdx.x;
  int mb = b * 512;
  int t0 = lane * 8;
  const float* p0 = Ct + (size_t)(0 + c) * 4096 + mb;
  const float* p1 = Ct + (size_t)(128 + c) * 4096 + mb;
  const float* p2 = Ct + (size_t)(256 + c) * 4096 + mb;
  float v[8];
#pragma unroll
  for (int i = 0; i < 8; i++) {
    int t = t0 + i;
    v[i] = (t < 494) ? (p0[t] + p1[t + 1] + p2[t + 2]) : NEG_INF;
  }
#pragma unroll
  for (int i = 1; i < 8; i++) v[i] = fmaxf(v[i], v[i - 1]);
  float x = v[7];
#pragma unroll
  for (int d = 1; d < 64; d <<= 1) {
    float y = __shfl_up(x, d);
    if (lane >= d) x = fmaxf(x, y);
  }
  float excl = __shfl_up(x, 1);
  if (lane == 0) excl = NEG_INF;
  float* pm = PM2 + (size_t)(b * 128 + c) * 512;
#pragma unroll
  for (int i = 0; i < 8; i++) {
    int t = t0 + i;
    if (t < 494) pm[t] = fmaxf(v[i], excl);
  }
  const float* s0 = Ct + (size_t)(768 + c) * 4096 + mb;
  const float* s1 = Ct + (size_t)(896 + c) * 4096 + mb;
  const float* s2 = Ct + (size_t)(1024 + c) * 4096 + mb;
  int qmax = wsl[b] - 3;
  if (qmax > 509) qmax = 509;
  float u[8];
#pragma unroll
  for (int i = 0; i < 8; i++) {
    int q = t0 + i;
    u[i] = (q <= qmax) ? (s0[q] + s1[q + 1] + s2[q + 2]) : NEG_INF;
  }
#pragma unroll
  for (int i = 6; i >= 0; i--) u[i] = fmaxf(u[i], u[i + 1]);
  float xr = u[0];
#pragma unroll
  for (int d = 1; d < 64; d <<= 1) {
    float y = __shfl_down(xr, d);
    if (lane < 64 - d) xr = fmaxf(xr, y);
  }
  float exclr = __shfl_down(xr, 1);
  if (lane == 63) exclr = NEG_INF;
  float* sm = SM2 + (size_t)(b * 128 + c) * 512;
#pragma unroll
  for (int i = 0; i < 8; i++) sm[t0 + i] = fmaxf(u[i], exclr);
}

// ---------------------------------------------------------------------------
// Kernel 4: per-span features + coalesced FC + sigmoid + threshold
// ---------------------------------------------------------------------------
__global__ __launch_bounds__(128) void span_kernel(
    const float* __restrict__ Ct, const float* __restrict__ PM2,
    const float* __restrict__ SM2, const float* __restrict__ prefix_b,
    const float* __restrict__ span_b, const float* __restrict__ suffix_b,
    const float* __restrict__ fcT, const float* __restrict__ fc_b,
    const int* __restrict__ spans, const int* __restrict__ wsl,
    float* __restrict__ out) {
  __shared__ float sfeat[384];
  __shared__ float part[64];
  int sp = blockIdx.x;
  int b = sp >> 5;
  int c = threadIdx.x;
  int s = spans[sp * 2], e = spans[sp * 2 + 1];
  int Lb = wsl[b];
  int mb = b * 512;
  {  // prefix window (T=496)
    const float* t0p = Ct + (size_t)c * 4096 + mb;
    const float* t1p = Ct + (size_t)(128 + c) * 4096 + mb;
    float m = NEG_INF;
    if (s >= 3) m = fmaxf(m, PM2[(size_t)(b * 128 + c) * 512 + s - 3]);
    if (s >= 2 && s <= 495) m = fmaxf(m, t0p[s - 2] + t1p[s - 1]);
    if (s >= 1 && s <= 494) m = fmaxf(m, t0p[s - 1]);
    if (s <= 493) m = fmaxf(m, 0.0f);
    sfeat[c] = m + prefix_b[c];
  }
  {  // span window (T=16)
    const float* u0 = Ct + (size_t)(384 + c) * 4096 + mb;
    const float* u1 = Ct + (size_t)(512 + c) * 4096 + mb;
    const float* u2 = Ct + (size_t)(640 + c) * 4096 + mb;
    int w = e - s;
    float m = NEG_INF;
    for (int p = 0; p + 2 < w; ++p)
      m = fmaxf(m, u0[s + p] + u1[s + p + 1] + u2[s + p + 2]);
    if (w >= 2 && w <= 15) m = fmaxf(m, u0[s + w - 2] + u1[s + w - 1]);
    if (w <= 14) m = fmaxf(m, u0[s + w - 1]);
    if (w <= 13) m = fmaxf(m, 0.0f);
    sfeat[128 + c] = m + span_b[c];
  }
  {  // suffix window (T=511)
    const float* x0 = Ct + (size_t)(768 + c) * 4096 + mb;
    const float* x1 = Ct + (size_t)(896 + c) * 4096 + mb;
    float m = NEG_INF;
    if (e <= Lb - 3) m = fmaxf(m, SM2[(size_t)(b * 128 + c) * 512 + e]);
    if (Lb - 2 - e >= 0 && Lb - 2 - e <= 508)
      m = fmaxf(m, x0[Lb - 2] + x1[Lb - 1]);
    if (Lb - 1 - e >= 0 && Lb - 1 - e <= 508) m = fmaxf(m, x0[Lb - 1]);
    if (Lb - e <= 508) m = fmaxf(m, 0.0f);
    sfeat[256 + c] = m + suffix_b[c];
  }
  __syncthreads();
  {  // FC: out[c] = sigmoid(fc_b[c] + sum_i sfeat[i]*fcT[i][c]), coalesced
    int cc = threadIdx.x & 63;
    int half = threadIdx.x >> 6;
    float acc2 = 0.0f;
    const float* fp = fcT + (size_t)(half * 192) * 64 + cc;
    const float* sf = sfeat + half * 192;
#pragma unroll 8
    for (int i = 0; i < 192; ++i) acc2 = fmaf(sf[i], fp[(size_t)i * 64], acc2);
    if (half) part[cc] = acc2;
    __syncthreads();
    if (!half) {
      float a = acc2 + part[cc] + fc_b[cc];
      float pr = 1.0f / (1.0f + expf(-a));
      out[sp * 64 + cc] = pr;
      out[16384 + sp * 64 + cc] = (pr > 0.5f) ? 1.0f : 0.0f;
    }
  }
}

// ---------------------------------------------------------------------------
extern "C" void kernel_launch(void* const* d_in, const int* in_sizes, int n_in,
                              void* d_out, int out_size, void* d_ws,
                              size_t ws_size, hipStream_t stream) {
  const float* tokens = (const float*)d_in[0];
  const float* span_w = (const float*)d_in[1];
  const float* span_b = (const float*)d_in[2];
  const float* prefix_w = (const float*)d_in[3];
  const float* prefix_b = (const float*)d_in[4];
  const float* suffix_w = (const float*)d_in[5];
  const float* suffix_b = (const float*)d_in[6];
  const float* fc_w = (const float*)d_in[7];
  const float* fc_b = (const float*)d_in[8];
  const int* spans = (const int*)d_in[9];
  const int* wsl = (const int*)d_in[10];
  float* out = (float*)d_out;

  char* ws = (char*)d_ws;
  float* Ct = (float*)ws;                       // 1152*4096*4 = 18874368 B
  float* Wt = (float*)(ws + 18874368);          // 768*1152*4  =  3538944 B
  float* PM2 = (float*)(ws + 22413312);         // 8*128*512*4 =  2097152 B
  float* SM2 = (float*)(ws + 24510464);         // 2097152 B
  float* fcT = (float*)(ws + 26607616);         // 384*64*4    =    98304 B

  hipLaunchKernelGGL(transpose_w, dim3(3552), dim3(256), 0, stream, span_w,
                     prefix_w, suffix_w, fc_w, Wt, fcT);
  hipLaunchKernelGGL(gemm_ct, dim3(18, 32), dim3(256), 0, stream, tokens, Wt,
                     Ct);
  hipLaunchKernelGGL(scan_kernel, dim3(1024), dim3(64), 0, stream, Ct, wsl,
                     PM2, SM2);
  hipLaunchKernelGGL(span_kernel, dim3(256), dim3(128), 0, stream, Ct, PM2,
                     SM2, prefix_b, span_b, suffix_b, fcT, fc_b, spans, wsl,
                     out);
}

// Round 3
// 160.988 us; speedup vs baseline: 1.4150x; 1.4051x over previous
//
#include <hip/hip_runtime.h>
#include <hip/hip_bf16.h>
#include <math.h>

// B=8, N=32, S=512, H=768, K=3, C=128, L=64, W=16
#define NEG_INF (-1e30f)

typedef _Float16 half8 __attribute__((ext_vector_type(8)));
typedef float f32x4 __attribute__((ext_vector_type(4)));

__device__ __forceinline__ void load_lds16(const void* g, void* l) {
  __builtin_amdgcn_global_load_lds((const __attribute__((address_space(1))) void*)g,
                                   (__attribute__((address_space(3))) void*)l, 16, 0, 0);
}

// ---------------------------------------------------------------------------
// Kernel 1 (prep): build
//   A2 [4096 x 2304] f16 = [A_hi | A_lo*2^6 | A_hi*2^-6]   (k-contiguous)
//   Bt [1152 x 2304] f16 = rows j, cols k: [B_hi | B_hi*2^-6 | B_lo*2^6]
//   fcT[i][c] fp32 (i<384, c<64)
// ---------------------------------------------------------------------------
__global__ __launch_bounds__(256) void prep(
    const float* __restrict__ tokens, const float* __restrict__ span_w,
    const float* __restrict__ prefix_w, const float* __restrict__ suffix_w,
    const float* __restrict__ fc_w, _Float16* __restrict__ A2,
    _Float16* __restrict__ Bt, float* __restrict__ fcT) {
  int bid = blockIdx.x;
  int t = threadIdx.x;
  if (bid < 12288) {  // A2: one thread per (m,h)
    int g = bid * 256 + t;  // m*768 + h
    int m = g / 768, h = g % 768;
    float x = tokens[g];
    _Float16 hi = (_Float16)x;
    _Float16 lo = (_Float16)((x - (float)hi) * 64.0f);
    _Float16 hi6 = (_Float16)((float)hi * 0.015625f);
    size_t base = (size_t)m * 2304 + h;
    A2[base] = hi;
    A2[base + 768] = lo;
    A2[base + 1536] = hi6;
  } else if (bid < 22656) {  // Bt: one thread per (j,k)
    int g = (bid - 12288) * 256 + t;  // j*2304 + k
    int j = g / 2304, k = g % 2304;
    int ws = j / 384, r = j % 384, tap = r / 128, c = r % 128;
    int reg = k / 768, h = k % 768;
    const float* wsrc = (ws == 0) ? prefix_w : (ws == 1) ? span_w : suffix_w;
    float w = wsrc[(c * 768 + h) * 3 + tap];
    _Float16 bhi = (_Float16)w;
    _Float16 o;
    if (reg == 0)
      o = bhi;
    else if (reg == 1)
      o = (_Float16)((float)bhi * 0.015625f);
    else
      o = (_Float16)((w - (float)bhi) * 64.0f);
    Bt[g] = o;
  } else {  // fcT
    int g = (bid - 22656) * 256 + t;  // i*64 + c  (24576 total)
    int i = g >> 6, c = g & 63;
    fcT[g] = fc_w[c * 384 + i];
  }
}

// ---------------------------------------------------------------------------
// Kernel 2: MFMA GEMM  Ct[j][m] = sum_k A2[m][k] * Bt[j][k]   (fp32 out)
//   M=4096, N=1152, K=2304. BM=64, BN=128, BK=32, 256 thr (4 waves).
//   Wave tile 32(m) x 64(j) = 2x4 mfma_f32_16x16x32_f16.
//   Staging via global_load_lds width-16 (wave-uniform base + lane*16).
// ---------------------------------------------------------------------------
__global__ __launch_bounds__(256) void gemm_f16(const _Float16* __restrict__ A2,
                                                const _Float16* __restrict__ Bt,
                                                float* __restrict__ Ct) {
  __shared__ _Float16 As[64 * 32];   // [m][k] row-major, 4 KB
  __shared__ _Float16 Bs[128 * 32];  // [j][k] row-major, 8 KB
  const int bm = blockIdx.x * 64;
  const int bj = blockIdx.y * 128;
  const int tid = threadIdx.x;
  const int w = tid >> 6;
  const int lane = tid & 63;
  const int row = tid >> 2;          // 0..63
  const int koff = (tid & 3) * 8;    // 0,8,16,24
  const _Float16* gA = A2 + (size_t)(bm + row) * 2304 + koff;
  const _Float16* gB0 = Bt + (size_t)(bj + row) * 2304 + koff;
  const _Float16* gB1 = Bt + (size_t)(bj + 64 + row) * 2304 + koff;
  _Float16* lA = As + w * 512;         // wave w stages A rows 16w..16w+15
  _Float16* lB0 = Bs + w * 512;        // B rows 16w..16w+15
  _Float16* lB1 = Bs + 2048 + w * 512; // B rows 64+16w..64+16w+15
  const int mrow = lane & 15;
  const int kq = (lane >> 4) * 8;
  const int m0w = (w & 1) * 32;
  const int n0w = (w >> 1) * 64;
  f32x4 acc[2][4];
#pragma unroll
  for (int i = 0; i < 2; ++i)
#pragma unroll
    for (int j = 0; j < 4; ++j) acc[i][j] = (f32x4){0.f, 0.f, 0.f, 0.f};

  for (int k0 = 0; k0 < 2304; k0 += 32) {
    __syncthreads();  // previous iter's LDS reads complete
    load_lds16(gA + k0, lA);
    load_lds16(gB0 + k0, lB0);
    load_lds16(gB1 + k0, lB1);
    __syncthreads();  // staging visible (compiler drains vmcnt before barrier)
    half8 a0 = *(const half8*)&As[(m0w + mrow) * 32 + kq];
    half8 a1 = *(const half8*)&As[(m0w + 16 + mrow) * 32 + kq];
#pragma unroll
    for (int nt = 0; nt < 4; ++nt) {
      half8 b = *(const half8*)&Bs[(n0w + nt * 16 + mrow) * 32 + kq];
      acc[0][nt] = __builtin_amdgcn_mfma_f32_16x16x32_f16(a0, b, acc[0][nt], 0, 0, 0);
      acc[1][nt] = __builtin_amdgcn_mfma_f32_16x16x32_f16(a1, b, acc[1][nt], 0, 0, 0);
    }
  }
  // C/D layout: m = (lane>>4)*4 + reg, n = lane&15  (dtype-independent, m89)
  const int mbase = bm + m0w + (lane >> 4) * 4;
#pragma unroll
  for (int mt = 0; mt < 2; ++mt)
#pragma unroll
    for (int nt = 0; nt < 4; ++nt) {
      int n_out = bj + n0w + nt * 16 + mrow;
      *(f32x4*)(Ct + (size_t)n_out * 4096 + mbase + mt * 16) = acc[mt][nt];
    }
}

// ---------------------------------------------------------------------------
// Kernel 3: per-(b,c) tap-combine + prefix-max / suffix-max scans
// ---------------------------------------------------------------------------
__global__ __launch_bounds__(64) void scan_kernel(const float* __restrict__ Ct,
                                                  const int* __restrict__ wsl,
                                                  float* __restrict__ PM2,
                                                  float* __restrict__ SM2) {
  int b = blockIdx.x >> 7;
  int c = blockIdx.x & 127;
  int lane = threadIdx.x;
  int mb = b * 512;
  int t0 = lane * 8;
  const float* p0 = Ct + (size_t)(0 + c) * 4096 + mb;
  const float* p1 = Ct + (size_t)(128 + c) * 4096 + mb;
  const float* p2 = Ct + (size_t)(256 + c) * 4096 + mb;
  float v[8];
#pragma unroll
  for (int i = 0; i < 8; i++) {
    int t = t0 + i;
    v[i] = (t < 494) ? (p0[t] + p1[t + 1] + p2[t + 2]) : NEG_INF;
  }
#pragma unroll
  for (int i = 1; i < 8; i++) v[i] = fmaxf(v[i], v[i - 1]);
  float x = v[7];
#pragma unroll
  for (int d = 1; d < 64; d <<= 1) {
    float y = __shfl_up(x, d);
    if (lane >= d) x = fmaxf(x, y);
  }
  float excl = __shfl_up(x, 1);
  if (lane == 0) excl = NEG_INF;
  float* pm = PM2 + (size_t)(b * 128 + c) * 512;
#pragma unroll
  for (int i = 0; i < 8; i++) {
    int t = t0 + i;
    if (t < 494) pm[t] = fmaxf(v[i], excl);
  }
  const float* s0 = Ct + (size_t)(768 + c) * 4096 + mb;
  const float* s1 = Ct + (size_t)(896 + c) * 4096 + mb;
  const float* s2 = Ct + (size_t)(1024 + c) * 4096 + mb;
  int qmax = wsl[b] - 3;
  if (qmax > 509) qmax = 509;
  float u[8];
#pragma unroll
  for (int i = 0; i < 8; i++) {
    int q = t0 + i;
    u[i] = (q <= qmax) ? (s0[q] + s1[q + 1] + s2[q + 2]) : NEG_INF;
  }
#pragma unroll
  for (int i = 6; i >= 0; i--) u[i] = fmaxf(u[i], u[i + 1]);
  float xr = u[0];
#pragma unroll
  for (int d = 1; d < 64; d <<= 1) {
    float y = __shfl_down(xr, d);
    if (lane < 64 - d) xr = fmaxf(xr, y);
  }
  float exclr = __shfl_down(xr, 1);
  if (lane == 63) exclr = NEG_INF;
  float* sm = SM2 + (size_t)(b * 128 + c) * 512;
#pragma unroll
  for (int i = 0; i < 8; i++) sm[t0 + i] = fmaxf(u[i], exclr);
}

// ---------------------------------------------------------------------------
// Kernel 4: per-span features + coalesced FC + sigmoid + threshold
// ---------------------------------------------------------------------------
__global__ __launch_bounds__(128) void span_kernel(
    const float* __restrict__ Ct, const float* __restrict__ PM2,
    const float* __restrict__ SM2, const float* __restrict__ prefix_b,
    const float* __restrict__ span_b, const float* __restrict__ suffix_b,
    const float* __restrict__ fcT, const float* __restrict__ fc_b,
    const int* __restrict__ spans, const int* __restrict__ wsl,
    float* __restrict__ out) {
  __shared__ float sfeat[384];
  __shared__ float part[64];
  int sp = blockIdx.x;
  int b = sp >> 5;
  int c = threadIdx.x;
  int s = spans[sp * 2], e = spans[sp * 2 + 1];
  int Lb = wsl[b];
  int mb = b * 512;
  {  // prefix window (T=496)
    const float* t0p = Ct + (size_t)c * 4096 + mb;
    const float* t1p = Ct + (size_t)(128 + c) * 4096 + mb;
    float m = NEG_INF;
    if (s >= 3) m = fmaxf(m, PM2[(size_t)(b * 128 + c) * 512 + s - 3]);
    if (s >= 2 && s <= 495) m = fmaxf(m, t0p[s - 2] + t1p[s - 1]);
    if (s >= 1 && s <= 494) m = fmaxf(m, t0p[s - 1]);
    if (s <= 493) m = fmaxf(m, 0.0f);
    sfeat[c] = m + prefix_b[c];
  }
  {  // span window (T=16)
    const float* u0 = Ct + (size_t)(384 + c) * 4096 + mb;
    const float* u1 = Ct + (size_t)(512 + c) * 4096 + mb;
    const float* u2 = Ct + (size_t)(640 + c) * 4096 + mb;
    int w = e - s;
    float m = NEG_INF;
    for (int p = 0; p + 2 < w; ++p)
      m = fmaxf(m, u0[s + p] + u1[s + p + 1] + u2[s + p + 2]);
    if (w >= 2 && w <= 15) m = fmaxf(m, u0[s + w - 2] + u1[s + w - 1]);
    if (w <= 14) m = fmaxf(m, u0[s + w - 1]);
    if (w <= 13) m = fmaxf(m, 0.0f);
    sfeat[128 + c] = m + span_b[c];
  }
  {  // suffix window (T=511)
    const float* x0 = Ct + (size_t)(768 + c) * 4096 + mb;
    const float* x1 = Ct + (size_t)(896 + c) * 4096 + mb;
    float m = NEG_INF;
    if (e <= Lb - 3) m = fmaxf(m, SM2[(size_t)(b * 128 + c) * 512 + e]);
    if (Lb - 2 - e >= 0 && Lb - 2 - e <= 508)
      m = fmaxf(m, x0[Lb - 2] + x1[Lb - 1]);
    if (Lb - 1 - e >= 0 && Lb - 1 - e <= 508) m = fmaxf(m, x0[Lb - 1]);
    if (Lb - e <= 508) m = fmaxf(m, 0.0f);
    sfeat[256 + c] = m + suffix_b[c];
  }
  __syncthreads();
  {  // FC: out[c] = sigmoid(fc_b[c] + sum_i sfeat[i]*fcT[i][c])
    int cc = threadIdx.x & 63;
    int half = threadIdx.x >> 6;
    float acc2 = 0.0f;
    const float* fp = fcT + (size_t)(half * 192) * 64 + cc;
    const float* sf = sfeat + half * 192;
#pragma unroll 8
    for (int i = 0; i < 192; ++i) acc2 = fmaf(sf[i], fp[(size_t)i * 64], acc2);
    if (half) part[cc] = acc2;
    __syncthreads();
    if (!half) {
      float a = acc2 + part[cc] + fc_b[cc];
      float pr = 1.0f / (1.0f + expf(-a));
      out[sp * 64 + cc] = pr;
      out[16384 + sp * 64 + cc] = (pr > 0.5f) ? 1.0f : 0.0f;
    }
  }
}

// ---------------------------------------------------------------------------
extern "C" void kernel_launch(void* const* d_in, const int* in_sizes, int n_in,
                              void* d_out, int out_size, void* d_ws,
                              size_t ws_size, hipStream_t stream) {
  const float* tokens = (const float*)d_in[0];
  const float* span_w = (const float*)d_in[1];
  const float* span_b = (const float*)d_in[2];
  const float* prefix_w = (const float*)d_in[3];
  const float* prefix_b = (const float*)d_in[4];
  const float* suffix_w = (const float*)d_in[5];
  const float* suffix_b = (const float*)d_in[6];
  const float* fc_w = (const float*)d_in[7];
  const float* fc_b = (const float*)d_in[8];
  const int* spans = (const int*)d_in[9];
  const int* wsl = (const int*)d_in[10];
  float* out = (float*)d_out;

  char* ws = (char*)d_ws;
  float* Ct = (float*)ws;                           // 1152*4096*4 = 18874368
  _Float16* A2 = (_Float16*)(ws + 18874368);        // 4096*2304*2 = 18874368
  _Float16* Bt = (_Float16*)(ws + 37748736);        // 1152*2304*2 =  5308416
  float* PM2 = (float*)(ws + 43057152);             // 8*128*512*4 =  2097152
  float* SM2 = (float*)(ws + 45154304);             //                2097152
  float* fcT = (float*)(ws + 47251456);             // 384*64*4    =    98304

  hipLaunchKernelGGL(prep, dim3(22752), dim3(256), 0, stream, tokens, span_w,
                     prefix_w, suffix_w, fc_w, A2, Bt, fcT);
  hipLaunchKernelGGL(gemm_f16, dim3(64, 9), dim3(256), 0, stream, A2, Bt, Ct);
  hipLaunchKernelGGL(scan_kernel, dim3(1024), dim3(64), 0, stream, Ct, wsl,
                     PM2, SM2);
  hipLaunchKernelGGL(span_kernel, dim3(256), dim3(128), 0, stream, Ct, PM2,
                     SM2, prefix_b, span_b, suffix_b, fcT, fc_b, spans, wsl,
                     out);
}

// Round 4
// 156.229 us; speedup vs baseline: 1.4581x; 1.0305x over previous
//
#include <hip/hip_runtime.h>
#include <hip/hip_bf16.h>
#include <math.h>

// B=8, N=32, S=512, H=768, K=3, C=128, L=64, W=16
#define NEG_INF (-1e30f)

typedef _Float16 half8 __attribute__((ext_vector_type(8)));
typedef _Float16 half4 __attribute__((ext_vector_type(4)));
typedef _Float16 half2v __attribute__((ext_vector_type(2)));
typedef float f32x4 __attribute__((ext_vector_type(4)));

__device__ __forceinline__ void load_lds16(const void* g, void* l) {
  __builtin_amdgcn_global_load_lds((const __attribute__((address_space(1))) void*)g,
                                   (__attribute__((address_space(3))) void*)l, 16, 0, 0);
}

// ---------------------------------------------------------------------------
// Kernel 1 (prep), vectorized:
//   A2 [4096 x 2304] f16 = [A_hi | A_lo*2^6 | A_hi*2^-6]  (4 elems/thread)
//   Bt [1152 x 2304] f16 (j-major) = [B_hi | B_hi*2^-6 | B_lo*2^6] (2 h/thread)
//   fcT[i][c] fp32
//   blocks: [0,3072) A2 | [3072,3648) Bt | [3648,3744) fcT
// ---------------------------------------------------------------------------
__global__ __launch_bounds__(256) void prep(
    const float* __restrict__ tokens, const float* __restrict__ span_w,
    const float* __restrict__ prefix_w, const float* __restrict__ suffix_w,
    const float* __restrict__ fc_w, _Float16* __restrict__ A2,
    _Float16* __restrict__ Bt, float* __restrict__ fcT) {
  int bid = blockIdx.x;
  int t = threadIdx.x;
  if (bid < 3072) {  // A2: 4 consecutive h per thread
    int g4 = (bid * 256 + t) * 4;  // m*768 + h, h%4==0
    int m = g4 / 768, h = g4 % 768;
    float4 x = *(const float4*)(tokens + g4);
    float xs[4] = {x.x, x.y, x.z, x.w};
    half4 hi, lo, hi6;
#pragma unroll
    for (int i = 0; i < 4; ++i) {
      _Float16 h_ = (_Float16)xs[i];
      hi[i] = h_;
      lo[i] = (_Float16)((xs[i] - (float)h_) * 64.0f);
      hi6[i] = (_Float16)((float)h_ * 0.015625f);
    }
    size_t base = (size_t)m * 2304 + h;
    *(half4*)(A2 + base) = hi;
    *(half4*)(A2 + base + 768) = lo;
    *(half4*)(A2 + base + 1536) = hi6;
  } else if (bid < 3648) {  // Bt: 2 consecutive h per thread
    int idx = (bid - 3072) * 256 + t;  // over 3*128*384
    int ws = idx / 49152;
    int r = idx % 49152;
    int c = r / 384, h = (r % 384) * 2;
    const float* wsrc = (ws == 0) ? prefix_w : (ws == 1) ? span_w : suffix_w;
    const float* wp = wsrc + (size_t)(c * 768 + h) * 3;
#pragma unroll
    for (int tap = 0; tap < 3; ++tap) {
      float w0 = wp[tap], w1 = wp[3 + tap];
      _Float16 h0 = (_Float16)w0, h1 = (_Float16)w1;
      half2v r0 = {h0, h1};
      half2v r1 = {(_Float16)((float)h0 * 0.015625f),
                   (_Float16)((float)h1 * 0.015625f)};
      half2v r2 = {(_Float16)((w0 - (float)h0) * 64.0f),
                   (_Float16)((w1 - (float)h1) * 64.0f)};
      size_t jb = (size_t)(ws * 384 + tap * 128 + c) * 2304 + h;
      *(half2v*)(Bt + jb) = r0;
      *(half2v*)(Bt + jb + 768) = r1;
      *(half2v*)(Bt + jb + 1536) = r2;
    }
  } else {  // fcT
    int g = (bid - 3648) * 256 + t;  // i*64 + c, 24576 total
    int i = g >> 6, c = g & 63;
    fcT[g] = fc_w[c * 384 + i];
  }
}

// ---------------------------------------------------------------------------
// Kernel 2: MFMA GEMM  Ct[j][m] = sum_k A2[m][k] * Bt[j][k]   (fp32 out)
//   M=4096, N=1152, K=2304. BM=64, BN=128, BK=32, 256 thr (4 waves).
//   Double-buffered LDS, ONE barrier/iter: prefetch k+1 issued after the
//   barrier, lands during compute of tile k (the barrier's vmcnt(0) drain
//   then waits on loads that had a full compute phase in flight).
// ---------------------------------------------------------------------------
__global__ __launch_bounds__(256) void gemm_f16(const _Float16* __restrict__ A2,
                                                const _Float16* __restrict__ Bt,
                                                float* __restrict__ Ct) {
  __shared__ _Float16 As[2][64 * 32];   // [buf][m][k], 2x4 KB
  __shared__ _Float16 Bs[2][128 * 32];  // [buf][j][k], 2x8 KB
  const int bm = blockIdx.x * 64;
  const int bj = blockIdx.y * 128;
  const int tid = threadIdx.x;
  const int w = tid >> 6;
  const int lane = tid & 63;
  const int row = tid >> 2;        // 0..63
  const int koff = (tid & 3) * 8;  // 0,8,16,24
  const _Float16* gA = A2 + (size_t)(bm + row) * 2304 + koff;
  const _Float16* gB0 = Bt + (size_t)(bj + row) * 2304 + koff;
  const _Float16* gB1 = Bt + (size_t)(bj + 64 + row) * 2304 + koff;
  const int mrow = lane & 15;
  const int kq = (lane >> 4) * 8;
  const int m0w = (w & 1) * 32;
  const int n0w = (w >> 1) * 64;
  f32x4 acc[2][4];
#pragma unroll
  for (int i = 0; i < 2; ++i)
#pragma unroll
    for (int j = 0; j < 4; ++j) acc[i][j] = (f32x4){0.f, 0.f, 0.f, 0.f};

  // prologue: stage tile 0 into buf 0
  load_lds16(gA, &As[0][w * 512]);
  load_lds16(gB0, &Bs[0][w * 512]);
  load_lds16(gB1, &Bs[0][2048 + w * 512]);

  int cur = 0;
  for (int k0 = 0; k0 < 2304; k0 += 32) {
    __syncthreads();  // tile k0 staged (prefetch had full compute phase)
    if (k0 + 32 < 2304) {
      int nxt = cur ^ 1;
      load_lds16(gA + k0 + 32, &As[nxt][w * 512]);
      load_lds16(gB0 + k0 + 32, &Bs[nxt][w * 512]);
      load_lds16(gB1 + k0 + 32, &Bs[nxt][2048 + w * 512]);
    }
    half8 a0 = *(const half8*)&As[cur][(m0w + mrow) * 32 + kq];
    half8 a1 = *(const half8*)&As[cur][(m0w + 16 + mrow) * 32 + kq];
#pragma unroll
    for (int nt = 0; nt < 4; ++nt) {
      half8 b = *(const half8*)&Bs[cur][(n0w + nt * 16 + mrow) * 32 + kq];
      acc[0][nt] = __builtin_amdgcn_mfma_f32_16x16x32_f16(a0, b, acc[0][nt], 0, 0, 0);
      acc[1][nt] = __builtin_amdgcn_mfma_f32_16x16x32_f16(a1, b, acc[1][nt], 0, 0, 0);
    }
    cur ^= 1;
  }
  // C/D layout: m = (lane>>4)*4 + reg, n = lane&15
  const int mbase = bm + m0w + (lane >> 4) * 4;
#pragma unroll
  for (int mt = 0; mt < 2; ++mt)
#pragma unroll
    for (int nt = 0; nt < 4; ++nt) {
      int n_out = bj + n0w + nt * 16 + mrow;
      *(f32x4*)(Ct + (size_t)n_out * 4096 + mbase + mt * 16) = acc[mt][nt];
    }
}

// ---------------------------------------------------------------------------
// Kernel 3: per-(b,c) tap-combine + prefix-max / suffix-max scans
//   256 threads = 4 independent wave-scans; 256 blocks.
// ---------------------------------------------------------------------------
__global__ __launch_bounds__(256) void scan_kernel(const float* __restrict__ Ct,
                                                   const int* __restrict__ wsl,
                                                   float* __restrict__ PM2,
                                                   float* __restrict__ SM2) {
  int pair = blockIdx.x * 4 + (threadIdx.x >> 6);
  int b = pair >> 7;
  int c = pair & 127;
  int lane = threadIdx.x & 63;
  int mb = b * 512;
  int t0 = lane * 8;
  const float* p0 = Ct + (size_t)(0 + c) * 4096 + mb;
  const float* p1 = Ct + (size_t)(128 + c) * 4096 + mb;
  const float* p2 = Ct + (size_t)(256 + c) * 4096 + mb;
  float v[8];
#pragma unroll
  for (int i = 0; i < 8; i++) {
    int t = t0 + i;
    v[i] = (t < 494) ? (p0[t] + p1[t + 1] + p2[t + 2]) : NEG_INF;
  }
#pragma unroll
  for (int i = 1; i < 8; i++) v[i] = fmaxf(v[i], v[i - 1]);
  float x = v[7];
#pragma unroll
  for (int d = 1; d < 64; d <<= 1) {
    float y = __shfl_up(x, d);
    if (lane >= d) x = fmaxf(x, y);
  }
  float excl = __shfl_up(x, 1);
  if (lane == 0) excl = NEG_INF;
  float* pm = PM2 + (size_t)pair * 512;
#pragma unroll
  for (int i = 0; i < 8; i++) {
    int t = t0 + i;
    if (t < 494) pm[t] = fmaxf(v[i], excl);
  }
  const float* s0 = Ct + (size_t)(768 + c) * 4096 + mb;
  const float* s1 = Ct + (size_t)(896 + c) * 4096 + mb;
  const float* s2 = Ct + (size_t)(1024 + c) * 4096 + mb;
  int qmax = wsl[b] - 3;
  if (qmax > 509) qmax = 509;
  float u[8];
#pragma unroll
  for (int i = 0; i < 8; i++) {
    int q = t0 + i;
    u[i] = (q <= qmax) ? (s0[q] + s1[q + 1] + s2[q + 2]) : NEG_INF;
  }
#pragma unroll
  for (int i = 6; i >= 0; i--) u[i] = fmaxf(u[i], u[i + 1]);
  float xr = u[0];
#pragma unroll
  for (int d = 1; d < 64; d <<= 1) {
    float y = __shfl_down(xr, d);
    if (lane < 64 - d) xr = fmaxf(xr, y);
  }
  float exclr = __shfl_down(xr, 1);
  if (lane == 63) exclr = NEG_INF;
  float* sm = SM2 + (size_t)pair * 512;
#pragma unroll
  for (int i = 0; i < 8; i++) sm[t0 + i] = fmaxf(u[i], exclr);
}

// ---------------------------------------------------------------------------
// Kernel 4: per-span features + coalesced FC + sigmoid + threshold
// ---------------------------------------------------------------------------
__global__ __launch_bounds__(128) void span_kernel(
    const float* __restrict__ Ct, const float* __restrict__ PM2,
    const float* __restrict__ SM2, const float* __restrict__ prefix_b,
    const float* __restrict__ span_b, const float* __restrict__ suffix_b,
    const float* __restrict__ fcT, const float* __restrict__ fc_b,
    const int* __restrict__ spans, const int* __restrict__ wsl,
    float* __restrict__ out) {
  __shared__ float sfeat[384];
  __shared__ float part[64];
  int sp = blockIdx.x;
  int b = sp >> 5;
  int c = threadIdx.x;
  int s = spans[sp * 2], e = spans[sp * 2 + 1];
  int Lb = wsl[b];
  int mb = b * 512;
  {  // prefix window (T=496)
    const float* t0p = Ct + (size_t)c * 4096 + mb;
    const float* t1p = Ct + (size_t)(128 + c) * 4096 + mb;
    float m = NEG_INF;
    if (s >= 3) m = fmaxf(m, PM2[(size_t)(b * 128 + c) * 512 + s - 3]);
    if (s >= 2 && s <= 495) m = fmaxf(m, t0p[s - 2] + t1p[s - 1]);
    if (s >= 1 && s <= 494) m = fmaxf(m, t0p[s - 1]);
    if (s <= 493) m = fmaxf(m, 0.0f);
    sfeat[c] = m + prefix_b[c];
  }
  {  // span window (T=16)
    const float* u0 = Ct + (size_t)(384 + c) * 4096 + mb;
    const float* u1 = Ct + (size_t)(512 + c) * 4096 + mb;
    const float* u2 = Ct + (size_t)(640 + c) * 4096 + mb;
    int w = e - s;
    float m = NEG_INF;
    for (int p = 0; p + 2 < w; ++p)
      m = fmaxf(m, u0[s + p] + u1[s + p + 1] + u2[s + p + 2]);
    if (w >= 2 && w <= 15) m = fmaxf(m, u0[s + w - 2] + u1[s + w - 1]);
    if (w <= 14) m = fmaxf(m, u0[s + w - 1]);
    if (w <= 13) m = fmaxf(m, 0.0f);
    sfeat[128 + c] = m + span_b[c];
  }
  {  // suffix window (T=511)
    const float* x0 = Ct + (size_t)(768 + c) * 4096 + mb;
    const float* x1 = Ct + (size_t)(896 + c) * 4096 + mb;
    float m = NEG_INF;
    if (e <= Lb - 3) m = fmaxf(m, SM2[(size_t)(b * 128 + c) * 512 + e]);
    if (Lb - 2 - e >= 0 && Lb - 2 - e <= 508)
      m = fmaxf(m, x0[Lb - 2] + x1[Lb - 1]);
    if (Lb - 1 - e >= 0 && Lb - 1 - e <= 508) m = fmaxf(m, x0[Lb - 1]);
    if (Lb - e <= 508) m = fmaxf(m, 0.0f);
    sfeat[256 + c] = m + suffix_b[c];
  }
  __syncthreads();
  {  // FC: out[c] = sigmoid(fc_b[c] + sum_i sfeat[i]*fcT[i][c])
    int cc = threadIdx.x & 63;
    int half = threadIdx.x >> 6;
    float acc2 = 0.0f;
    const float* fp = fcT + (size_t)(half * 192) * 64 + cc;
    const float* sf = sfeat + half * 192;
#pragma unroll 8
    for (int i = 0; i < 192; ++i) acc2 = fmaf(sf[i], fp[(size_t)i * 64], acc2);
    if (half) part[cc] = acc2;
    __syncthreads();
    if (!half) {
      float a = acc2 + part[cc] + fc_b[cc];
      float pr = 1.0f / (1.0f + expf(-a));
      out[sp * 64 + cc] = pr;
      out[16384 + sp * 64 + cc] = (pr > 0.5f) ? 1.0f : 0.0f;
    }
  }
}

// ---------------------------------------------------------------------------
extern "C" void kernel_launch(void* const* d_in, const int* in_sizes, int n_in,
                              void* d_out, int out_size, void* d_ws,
                              size_t ws_size, hipStream_t stream) {
  const float* tokens = (const float*)d_in[0];
  const float* span_w = (const float*)d_in[1];
  const float* span_b = (const float*)d_in[2];
  const float* prefix_w = (const float*)d_in[3];
  const float* prefix_b = (const float*)d_in[4];
  const float* suffix_w = (const float*)d_in[5];
  const float* suffix_b = (const float*)d_in[6];
  const float* fc_w = (const float*)d_in[7];
  const float* fc_b = (const float*)d_in[8];
  const int* spans = (const int*)d_in[9];
  const int* wsl = (const int*)d_in[10];
  float* out = (float*)d_out;

  char* ws = (char*)d_ws;
  float* Ct = (float*)ws;                     // 1152*4096*4 = 18874368
  _Float16* A2 = (_Float16*)(ws + 18874368);  // 4096*2304*2 = 18874368
  _Float16* Bt = (_Float16*)(ws + 37748736);  // 1152*2304*2 =  5308416
  float* PM2 = (float*)(ws + 43057152);       // 8*128*512*4 =  2097152
  float* SM2 = (float*)(ws + 45154304);       //                2097152
  float* fcT = (float*)(ws + 47251456);       // 384*64*4    =    98304

  hipLaunchKernelGGL(prep, dim3(3744), dim3(256), 0, stream, tokens, span_w,
                     prefix_w, suffix_w, fc_w, A2, Bt, fcT);
  hipLaunchKernelGGL(gemm_f16, dim3(64, 9), dim3(256), 0, stream, A2, Bt, Ct);
  hipLaunchKernelGGL(scan_kernel, dim3(256), dim3(256), 0, stream, Ct, wsl,
                     PM2, SM2);
  hipLaunchKernelGGL(span_kernel, dim3(256), dim3(128), 0, stream, Ct, PM2,
                     SM2, prefix_b, span_b, suffix_b, fcT, fc_b, spans, wsl,
                     out);
}

// Round 5
// 153.347 us; speedup vs baseline: 1.4855x; 1.0188x over previous
//
#include <hip/hip_runtime.h>
#include <hip/hip_bf16.h>
#include <math.h>

// B=8, N=32, S=512, H=768, K=3, C=128, L=64, W=16
#define NEG_INF (-1e30f)

typedef _Float16 half8 __attribute__((ext_vector_type(8)));
typedef _Float16 half4 __attribute__((ext_vector_type(4)));
typedef float f32x4 __attribute__((ext_vector_type(4)));

__device__ __forceinline__ void load_lds16(const void* g, void* l) {
  __builtin_amdgcn_global_load_lds((const __attribute__((address_space(1))) void*)g,
                                   (__attribute__((address_space(3))) void*)l, 16, 0, 0);
}

// ---------------------------------------------------------------------------
// Kernel 1 (prep):
//   A2 [4096 x 2304] f16 = [A_hi | A_lo*2^6 | A_hi*2^-6]  (4 elems/thread)
//   Bt [1152 x 2304] f16 (j-major) = [B_hi | B_hi*2^-6 | B_lo*2^6]
//     thread = (ws, c, h8): 6 float4 contiguous loads -> 9 half8 stores
//   fcT[i][c] fp32
//   blocks: [0,3072) A2 | [3072,3216) Bt | [3216,3312) fcT
// ---------------------------------------------------------------------------
__global__ __launch_bounds__(256) void prep(
    const float* __restrict__ tokens, const float* __restrict__ span_w,
    const float* __restrict__ prefix_w, const float* __restrict__ suffix_w,
    const float* __restrict__ fc_w, _Float16* __restrict__ A2,
    _Float16* __restrict__ Bt, float* __restrict__ fcT) {
  int bid = blockIdx.x;
  int t = threadIdx.x;
  if (bid < 3072) {  // A2: 4 consecutive h per thread
    int g4 = (bid * 256 + t) * 4;  // m*768 + h, h%4==0
    int m = g4 / 768, h = g4 % 768;
    float4 x = *(const float4*)(tokens + g4);
    float xs[4] = {x.x, x.y, x.z, x.w};
    half4 hi, lo, hi6;
#pragma unroll
    for (int i = 0; i < 4; ++i) {
      _Float16 h_ = (_Float16)xs[i];
      hi[i] = h_;
      lo[i] = (_Float16)((xs[i] - (float)h_) * 64.0f);
      hi6[i] = (_Float16)((float)h_ * 0.015625f);
    }
    size_t base = (size_t)m * 2304 + h;
    *(half4*)(A2 + base) = hi;
    *(half4*)(A2 + base + 768) = lo;
    *(half4*)(A2 + base + 1536) = hi6;
  } else if (bid < 3216) {  // Bt: 8 h x 3 taps per thread, coalesced
    int g = (bid - 3072) * 256 + t;  // over 3*128*96 = 36864
    int ws = g / 12288;
    int r = g % 12288;
    int c = r / 96, h = (r % 96) * 8;
    const float* wsrc = (ws == 0) ? prefix_w : (ws == 1) ? span_w : suffix_w;
    const float* src = wsrc + (size_t)(c * 768 + h) * 3;  // 24 floats
    float wv[24];
#pragma unroll
    for (int i = 0; i < 6; ++i) *(float4*)&wv[i * 4] = *(const float4*)(src + i * 4);
#pragma unroll
    for (int tap = 0; tap < 3; ++tap) {
      half8 hi, lo, hi6;
#pragma unroll
      for (int i = 0; i < 8; ++i) {
        float x = wv[i * 3 + tap];
        _Float16 h_ = (_Float16)x;
        hi[i] = h_;
        lo[i] = (_Float16)((x - (float)h_) * 64.0f);
        hi6[i] = (_Float16)((float)h_ * 0.015625f);
      }
      size_t jb = (size_t)(ws * 384 + tap * 128 + c) * 2304 + h;
      *(half8*)(Bt + jb) = hi;
      *(half8*)(Bt + jb + 768) = hi6;
      *(half8*)(Bt + jb + 1536) = lo;
    }
  } else {  // fcT
    int g = (bid - 3216) * 256 + t;  // i*64 + c, 24576 total
    int i = g >> 6, c = g & 63;
    fcT[g] = fc_w[c * 384 + i];
  }
}

// ---------------------------------------------------------------------------
// Kernel 2: MFMA GEMM  Ct[j][m] = sum_k A2[m][k] * Bt[j][k]   (fp32 out)
//   M=4096, N=1152, K=2304. BM=64, BN=128, BK=64, 256 thr (4 waves).
//   Double-buffered (one barrier/iter, 36 iters, 16 MFMA/wave/iter).
//   LDS rows are 64 halfs; 16B chunks XOR-swizzled (chunk ^ row&7) so
//   ds_read_b128 fragment reads spread all 32 banks while the
//   global_load_lds staging stays packed (uniform base + lane*16).
// ---------------------------------------------------------------------------
__global__ __launch_bounds__(256) void gemm_f16(const _Float16* __restrict__ A2,
                                                const _Float16* __restrict__ Bt,
                                                float* __restrict__ Ct) {
  __shared__ _Float16 As[2][64 * 64];   // 2 x 8 KB
  __shared__ _Float16 Bs[2][128 * 64];  // 2 x 16 KB
  const int bm = blockIdx.x * 64;
  const int bj = blockIdx.y * 128;
  const int tid = threadIdx.x;
  const int w = tid >> 6;
  const int lane = tid & 63;
  const int lr = lane >> 3;       // staging row within 8-row group
  const int kcs = (lane & 7) ^ lr;  // swizzled 16B chunk this lane fetches
  const _Float16* gA = A2 + (size_t)(bm + w * 8 + lr) * 2304 + kcs * 8;
  const _Float16* gB = Bt + (size_t)(bj + w * 8 + lr) * 2304 + kcs * 8;
  // fragment read constants
  const int mrow = lane & 15;
  const int qb = lane >> 4;   // k-quad 0..3
  const int sw = lane & 7;    // row&7 of every fragment row this lane reads
  const int m0w = (w & 1) * 32;
  const int n0w = (w >> 1) * 64;
  const int co0 = (qb ^ sw) * 8;        // substep 0 chunk offset (halfs)
  const int co1 = ((qb + 4) ^ sw) * 8;  // substep 1
  f32x4 acc[2][4];
#pragma unroll
  for (int i = 0; i < 2; ++i)
#pragma unroll
    for (int j = 0; j < 4; ++j) acc[i][j] = (f32x4){0.f, 0.f, 0.f, 0.f};

  // prologue: stage tile 0 into buf 0
  load_lds16(gA, &As[0][w * 512]);
  load_lds16(gA + 32 * 2304, &As[0][2048 + w * 512]);
#pragma unroll
  for (int p = 0; p < 4; ++p)
    load_lds16(gB + (size_t)p * 32 * 2304, &Bs[0][p * 2048 + w * 512]);

  int cur = 0;
  for (int k0 = 0; k0 < 2304; k0 += 64) {
    __syncthreads();  // tile k0 staged; prefetch had a full compute phase
    if (k0 + 64 < 2304) {
      int nxt = cur ^ 1;
      load_lds16(gA + k0 + 64, &As[nxt][w * 512]);
      load_lds16(gA + k0 + 64 + 32 * 2304, &As[nxt][2048 + w * 512]);
#pragma unroll
      for (int p = 0; p < 4; ++p)
        load_lds16(gB + k0 + 64 + (size_t)p * 32 * 2304,
                   &Bs[nxt][p * 2048 + w * 512]);
    }
#pragma unroll
    for (int ks = 0; ks < 2; ++ks) {
      const int co = ks ? co1 : co0;
      half8 a0 = *(const half8*)&As[cur][(m0w + mrow) * 64 + co];
      half8 a1 = *(const half8*)&As[cur][(m0w + 16 + mrow) * 64 + co];
#pragma unroll
      for (int nt = 0; nt < 4; ++nt) {
        half8 b = *(const half8*)&Bs[cur][(n0w + nt * 16 + mrow) * 64 + co];
        acc[0][nt] = __builtin_amdgcn_mfma_f32_16x16x32_f16(a0, b, acc[0][nt], 0, 0, 0);
        acc[1][nt] = __builtin_amdgcn_mfma_f32_16x16x32_f16(a1, b, acc[1][nt], 0, 0, 0);
      }
    }
    cur ^= 1;
  }
  // C/D layout: m = (lane>>4)*4 + reg, n = lane&15
  const int mbase = bm + m0w + (lane >> 4) * 4;
#pragma unroll
  for (int mt = 0; mt < 2; ++mt)
#pragma unroll
    for (int nt = 0; nt < 4; ++nt) {
      int n_out = bj + n0w + nt * 16 + mrow;
      *(f32x4*)(Ct + (size_t)n_out * 4096 + mbase + mt * 16) = acc[mt][nt];
    }
}

// ---------------------------------------------------------------------------
// Kernel 3: per-(b,c) tap-combine + prefix-max / suffix-max scans
//   256 threads = 4 independent wave-scans; 256 blocks.
// ---------------------------------------------------------------------------
__global__ __launch_bounds__(256) void scan_kernel(const float* __restrict__ Ct,
                                                   const int* __restrict__ wsl,
                                                   float* __restrict__ PM2,
                                                   float* __restrict__ SM2) {
  int pair = blockIdx.x * 4 + (threadIdx.x >> 6);
  int b = pair >> 7;
  int c = pair & 127;
  int lane = threadIdx.x & 63;
  int mb = b * 512;
  int t0 = lane * 8;
  const float* p0 = Ct + (size_t)(0 + c) * 4096 + mb;
  const float* p1 = Ct + (size_t)(128 + c) * 4096 + mb;
  const float* p2 = Ct + (size_t)(256 + c) * 4096 + mb;
  float v[8];
#pragma unroll
  for (int i = 0; i < 8; i++) {
    int t = t0 + i;
    v[i] = (t < 494) ? (p0[t] + p1[t + 1] + p2[t + 2]) : NEG_INF;
  }
#pragma unroll
  for (int i = 1; i < 8; i++) v[i] = fmaxf(v[i], v[i - 1]);
  float x = v[7];
#pragma unroll
  for (int d = 1; d < 64; d <<= 1) {
    float y = __shfl_up(x, d);
    if (lane >= d) x = fmaxf(x, y);
  }
  float excl = __shfl_up(x, 1);
  if (lane == 0) excl = NEG_INF;
  float* pm = PM2 + (size_t)pair * 512;
#pragma unroll
  for (int i = 0; i < 8; i++) {
    int t = t0 + i;
    if (t < 494) pm[t] = fmaxf(v[i], excl);
  }
  const float* s0 = Ct + (size_t)(768 + c) * 4096 + mb;
  const float* s1 = Ct + (size_t)(896 + c) * 4096 + mb;
  const float* s2 = Ct + (size_t)(1024 + c) * 4096 + mb;
  int qmax = wsl[b] - 3;
  if (qmax > 509) qmax = 509;
  float u[8];
#pragma unroll
  for (int i = 0; i < 8; i++) {
    int q = t0 + i;
    u[i] = (q <= qmax) ? (s0[q] + s1[q + 1] + s2[q + 2]) : NEG_INF;
  }
#pragma unroll
  for (int i = 6; i >= 0; i--) u[i] = fmaxf(u[i], u[i + 1]);
  float xr = u[0];
#pragma unroll
  for (int d = 1; d < 64; d <<= 1) {
    float y = __shfl_down(xr, d);
    if (lane < 64 - d) xr = fmaxf(xr, y);
  }
  float exclr = __shfl_down(xr, 1);
  if (lane == 63) exclr = NEG_INF;
  float* sm = SM2 + (size_t)pair * 512;
#pragma unroll
  for (int i = 0; i < 8; i++) sm[t0 + i] = fmaxf(u[i], exclr);
}

// ---------------------------------------------------------------------------
// Kernel 4: per-span features + coalesced FC + sigmoid + threshold
// ---------------------------------------------------------------------------
__global__ __launch_bounds__(128) void span_kernel(
    const float* __restrict__ Ct, const float* __restrict__ PM2,
    const float* __restrict__ SM2, const float* __restrict__ prefix_b,
    const float* __restrict__ span_b, const float* __restrict__ suffix_b,
    const float* __restrict__ fcT, const float* __restrict__ fc_b,
    const int* __restrict__ spans, const int* __restrict__ wsl,
    float* __restrict__ out) {
  __shared__ float sfeat[384];
  __shared__ float part[64];
  int sp = blockIdx.x;
  int b = sp >> 5;
  int c = threadIdx.x;
  int s = spans[sp * 2], e = spans[sp * 2 + 1];
  int Lb = wsl[b];
  int mb = b * 512;
  {  // prefix window (T=496)
    const float* t0p = Ct + (size_t)c * 4096 + mb;
    const float* t1p = Ct + (size_t)(128 + c) * 4096 + mb;
    float m = NEG_INF;
    if (s >= 3) m = fmaxf(m, PM2[(size_t)(b * 128 + c) * 512 + s - 3]);
    if (s >= 2 && s <= 495) m = fmaxf(m, t0p[s - 2] + t1p[s - 1]);
    if (s >= 1 && s <= 494) m = fmaxf(m, t0p[s - 1]);
    if (s <= 493) m = fmaxf(m, 0.0f);
    sfeat[c] = m + prefix_b[c];
  }
  {  // span window (T=16)
    const float* u0 = Ct + (size_t)(384 + c) * 4096 + mb;
    const float* u1 = Ct + (size_t)(512 + c) * 4096 + mb;
    const float* u2 = Ct + (size_t)(640 + c) * 4096 + mb;
    int w = e - s;
    float m = NEG_INF;
    for (int p = 0; p + 2 < w; ++p)
      m = fmaxf(m, u0[s + p] + u1[s + p + 1] + u2[s + p + 2]);
    if (w >= 2 && w <= 15) m = fmaxf(m, u0[s + w - 2] + u1[s + w - 1]);
    if (w <= 14) m = fmaxf(m, u0[s + w - 1]);
    if (w <= 13) m = fmaxf(m, 0.0f);
    sfeat[128 + c] = m + span_b[c];
  }
  {  // suffix window (T=511)
    const float* x0 = Ct + (size_t)(768 + c) * 4096 + mb;
    const float* x1 = Ct + (size_t)(896 + c) * 4096 + mb;
    float m = NEG_INF;
    if (e <= Lb - 3) m = fmaxf(m, SM2[(size_t)(b * 128 + c) * 512 + e]);
    if (Lb - 2 - e >= 0 && Lb - 2 - e <= 508)
      m = fmaxf(m, x0[Lb - 2] + x1[Lb - 1]);
    if (Lb - 1 - e >= 0 && Lb - 1 - e <= 508) m = fmaxf(m, x0[Lb - 1]);
    if (Lb - e <= 508) m = fmaxf(m, 0.0f);
    sfeat[256 + c] = m + suffix_b[c];
  }
  __syncthreads();
  {  // FC: out[c] = sigmoid(fc_b[c] + sum_i sfeat[i]*fcT[i][c])
    int cc = threadIdx.x & 63;
    int half = threadIdx.x >> 6;
    float acc2 = 0.0f;
    const float* fp = fcT + (size_t)(half * 192) * 64 + cc;
    const float* sf = sfeat + half * 192;
#pragma unroll 8
    for (int i = 0; i < 192; ++i) acc2 = fmaf(sf[i], fp[(size_t)i * 64], acc2);
    if (half) part[cc] = acc2;
    __syncthreads();
    if (!half) {
      float a = acc2 + part[cc] + fc_b[cc];
      float pr = 1.0f / (1.0f + expf(-a));
      out[sp * 64 + cc] = pr;
      out[16384 + sp * 64 + cc] = (pr > 0.5f) ? 1.0f : 0.0f;
    }
  }
}

// ---------------------------------------------------------------------------
extern "C" void kernel_launch(void* const* d_in, const int* in_sizes, int n_in,
                              void* d_out, int out_size, void* d_ws,
                              size_t ws_size, hipStream_t stream) {
  const float* tokens = (const float*)d_in[0];
  const float* span_w = (const float*)d_in[1];
  const float* span_b = (const float*)d_in[2];
  const float* prefix_w = (const float*)d_in[3];
  const float* prefix_b = (const float*)d_in[4];
  const float* suffix_w = (const float*)d_in[5];
  const float* suffix_b = (const float*)d_in[6];
  const float* fc_w = (const float*)d_in[7];
  const float* fc_b = (const float*)d_in[8];
  const int* spans = (const int*)d_in[9];
  const int* wsl = (const int*)d_in[10];
  float* out = (float*)d_out;

  char* ws = (char*)d_ws;
  float* Ct = (float*)ws;                     // 1152*4096*4 = 18874368
  _Float16* A2 = (_Float16*)(ws + 18874368);  // 4096*2304*2 = 18874368
  _Float16* Bt = (_Float16*)(ws + 37748736);  // 1152*2304*2 =  5308416
  float* PM2 = (float*)(ws + 43057152);       // 8*128*512*4 =  2097152
  float* SM2 = (float*)(ws + 45154304);       //                2097152
  float* fcT = (float*)(ws + 47251456);       // 384*64*4    =    98304

  hipLaunchKernelGGL(prep, dim3(3312), dim3(256), 0, stream, tokens, span_w,
                     prefix_w, suffix_w, fc_w, A2, Bt, fcT);
  hipLaunchKernelGGL(gemm_f16, dim3(64, 9), dim3(256), 0, stream, A2, Bt, Ct);
  hipLaunchKernelGGL(scan_kernel, dim3(256), dim3(256), 0, stream, Ct, wsl,
                     PM2, SM2);
  hipLaunchKernelGGL(span_kernel, dim3(256), dim3(128), 0, stream, Ct, PM2,
                     SM2, prefix_b, span_b, suffix_b, fcT, fc_b, spans, wsl,
                     out);
}